// Round 12
// baseline (646.688 us; speedup 1.0000x reference)
//
#include <hip/hip_runtime.h>

#define D      128
#define NCLI   100000
#define NAGG   1000
#define NLAYER 3
#define NBKT   782   // ceil(NCLI/128) buckets for a2c
#define NRNG   8     // src ranges for c2a (12500 clients each, 3.2 MB slice/XCD-L2)
#define NBIN   (NAGG * NRNG)   // 8000, layout bin = range*NAGG + dst
#define RMAGIC 343598u         // ceil(2^32/12500): r = umulhi(src, RMAGIC), exact for src<100000
#define NHIST  512
#define NCVTX  (NCLI * D / 4 / 256)   // 12500
#define NCVTW  ((NLAYER * D * D + 255) / 256)  // 192
#define NROWT  (NCLI / 32)            // 3125 row-tiles (exact)

typedef short bf16x8 __attribute__((ext_vector_type(8)));
typedef float f32x16 __attribute__((ext_vector_type(16)));

static __device__ __forceinline__ float leaky(float x) { return x >= 0.f ? x : 0.1f * x; }

// ---- bf16 pack/unpack (RNE) ----
static __device__ __forceinline__ unsigned bf16_rn(float f) {
    unsigned u = __float_as_uint(f);
    return (u + 0x7fffu + ((u >> 16) & 1u)) >> 16;
}
static __device__ __forceinline__ float bf_val(unsigned h) { return __uint_as_float(h << 16); }
static __device__ __forceinline__ unsigned pack_bf2(float lo, float hi) {
    return bf16_rn(lo) | (bf16_rn(hi) << 16);
}
static __device__ __forceinline__ float bf_lo(unsigned v) { return __uint_as_float(v << 16); }
static __device__ __forceinline__ float bf_hi(unsigned v) { return __uint_as_float(v & 0xffff0000u); }

// ---------------- phase 1: hist + feature/weight cvt, one launch ----------------
__global__ __launch_bounds__(256) void prep(const int* __restrict__ c2a_src,
                                            const int* __restrict__ c2a_dst,
                                            const int* __restrict__ a2c_dst, int E,
                                            int* __restrict__ cnt_ar, int* __restrict__ bcnt,
                                            const float4* __restrict__ X4,
                                            uint2* __restrict__ xhi, uint2* __restrict__ xlo,
                                            const float* __restrict__ W,
                                            unsigned short* __restrict__ Wt) {
    __shared__ int h[NBIN + NBKT];   // 35 KB
    int bid = blockIdx.x;
    if (bid < NHIST) {
        for (int i = threadIdx.x; i < NBIN + NBKT; i += 256) h[i] = 0;
        __syncthreads();
        int stride = NHIST * 256;
        for (int e = bid * 256 + threadIdx.x; e < E; e += stride) {
            int s = c2a_src[e];
            int bin = (int)__umulhi((unsigned)s, RMAGIC) * NAGG + c2a_dst[e];
            atomicAdd(&h[bin], 1);
            atomicAdd(&h[NBIN + (a2c_dst[e] >> 7)], 1);
        }
        __syncthreads();
        for (int i = threadIdx.x; i < NBIN; i += 256)
            if (h[i]) atomicAdd(&cnt_ar[i], h[i]);
        for (int i = threadIdx.x; i < NBKT; i += 256)
            if (h[NBIN + i]) atomicAdd(&bcnt[i], h[NBIN + i]);
    } else if (bid < NHIST + NCVTX) {
        int t = (bid - NHIST) * 256 + threadIdx.x;
        float4 f = X4[t];
        unsigned h0 = bf16_rn(f.x), h1 = bf16_rn(f.y), h2 = bf16_rn(f.z), h3 = bf16_rn(f.w);
        xhi[t] = make_uint2(h0 | (h1 << 16), h2 | (h3 << 16));
        xlo[t] = make_uint2(pack_bf2(f.x - bf_val(h0), f.y - bf_val(h1)),
                            pack_bf2(f.z - bf_val(h2), f.w - bf_val(h3)));
    } else {
        int idx = (bid - NHIST - NCVTX) * 256 + threadIdx.x;
        if (idx >= NLAYER * D * D) return;
        int layer = idx >> 14, rem = idx & (D * D - 1);
        int k = rem >> 7, n = rem & 127;
        float w = W[layer * D * D + k * D + n];
        unsigned hh = bf16_rn(w);
        unsigned short* base = Wt + layer * 2 * D * D;
        base[n * D + k] = (unsigned short)hh;
        base[D * D + n * D + k] = (unsigned short)bf16_rn(w - bf_val(hh));
    }
}

// ---------------- phase 2: scans ----------------
// block 0: scan cnt_ar[8000] -> rp_ar[8001] (starts) + cur_ar[8000] + cur_r8[8] (range starts)
// block 1: scan bcnt[782]    -> brp[783] + bcur[782]
__global__ void scan_both(const int* __restrict__ cnt_ar, int* __restrict__ rp_ar,
                          int* __restrict__ cur_ar, int* __restrict__ cur_r8,
                          const int* __restrict__ bcnt,
                          int* __restrict__ brp, int* __restrict__ bcur) {
    __shared__ int sh[1024];
    int t = threadIdx.x;
    if (blockIdx.x == 0) {
        int v[8];
        int s = 0;
#pragma unroll
        for (int j = 0; j < 8; j++) {
            int idx = t * 8 + j;
            v[j] = (idx < NBIN) ? cnt_ar[idx] : 0;
            s += v[j];
        }
        sh[t] = s;
        __syncthreads();
        for (int off = 1; off < 1024; off <<= 1) {
            int x = (t >= off) ? sh[t - off] : 0;
            __syncthreads();
            sh[t] += x;
            __syncthreads();
        }
        int run = sh[t] - s;  // exclusive prefix of this thread's chunk
#pragma unroll
        for (int j = 0; j < 8; j++) {
            int idx = t * 8 + j;
            if (idx < NBIN) {
                rp_ar[idx] = run;
                cur_ar[idx] = run;
                if ((idx % NAGG) == 0) cur_r8[idx / NAGG] = run;  // range starts
            }
            run += v[j];
        }
        if (t == 1023) rp_ar[NBIN] = sh[1023];
    } else {
        int v = (t < NBKT) ? bcnt[t] : 0;
        sh[t] = v;
        __syncthreads();
        for (int off = 1; off < 1024; off <<= 1) {
            int x = (t >= off) ? sh[t - off] : 0;
            __syncthreads();
            sh[t] += x;
            __syncthreads();
        }
        if (t == 0) { brp[0] = 0; bcur[0] = 0; }
        if (t < NBKT) {
            brp[t + 1] = sh[t];
            if (t + 1 < NBKT) bcur[t + 1] = sh[t];
        }
    }
}

// ---------------- phase 3a: scatter1 ----------------
// blocks [0,64): c2a pass1 — bucket by src-range (8 bins) via wave-ballot counting;
//   writes packed (dst<<17)|src grouped by range into sorted_c2a.
// blocks [64,320): a2c bucket scatter (dst>>7), as before.
__global__ __launch_bounds__(1024) void scatter1(const int* __restrict__ c2a_src,
                                                 const int* __restrict__ c2a_dst,
                                                 const int* __restrict__ a2c_src,
                                                 const int* __restrict__ a2c_dst, int E,
                                                 int* __restrict__ cur_r8,
                                                 int* __restrict__ sorted_c2a,
                                                 int* __restrict__ bcur,
                                                 int* __restrict__ sorted1) {
    __shared__ int sbuf[2 * NBKT];
    int tid = threadIdx.x;
    if (blockIdx.x < 64) {
        int* h = sbuf;         // [8]
        int* base = sbuf + 8;  // [8]
        int chunk = (E + 63) / 64;
        int e0 = blockIdx.x * chunk;
        int e1 = min(E, e0 + chunk);
        int wid = tid >> 6, lane = tid & 63;
        unsigned long long below = (1ull << lane) - 1;
        if (tid < 8) h[tid] = 0;
        __syncthreads();
        // phase A: count ranges (ballot per 64-edge strip)
        for (int eb = e0 + wid * 64; eb < e1; eb += 16 * 64) {
            int e = eb + lane;
            bool valid = e < e1;
            int s = valid ? c2a_src[e] : 0;
            int rg = (int)__umulhi((unsigned)s, RMAGIC);
#pragma unroll
            for (int r = 0; r < NRNG; r++) {
                unsigned long long m = __ballot(valid && rg == r);
                if (lane == r && m) atomicAdd(&h[r], __popcll(m));
            }
        }
        __syncthreads();
        if (tid < 8) base[tid] = h[tid] ? atomicAdd(&cur_r8[tid], h[tid]) : 0;
        __syncthreads();
        // phase C: scatter
        for (int eb = e0 + wid * 64; eb < e1; eb += 16 * 64) {
            int e = eb + lane;
            bool valid = e < e1;
            int s = valid ? c2a_src[e] : 0;
            int dcl = valid ? c2a_dst[e] : 0;
            int rg = (int)__umulhi((unsigned)s, RMAGIC);
            unsigned long long mym = 0;
            int wb = 0;
#pragma unroll
            for (int r = 0; r < NRNG; r++) {
                unsigned long long m = __ballot(valid && rg == r);
                if (valid && rg == r) mym = m;
                if (lane == r) wb = m ? atomicAdd(&base[r], __popcll(m)) : 0;
            }
            int pb = __shfl(wb, rg);
            if (valid) sorted_c2a[pb + __popcll(mym & below)] = (dcl << 17) | s;
        }
    } else {
        int* h = sbuf;
        int* base = sbuf + NBKT;
        int bid = blockIdx.x - 64;
        int chunk = (E + 255) / 256;
        int e0 = bid * chunk;
        int e1 = min(E, e0 + chunk);
        for (int i = tid; i < NBKT; i += 1024) h[i] = 0;
        __syncthreads();
        for (int e = e0 + tid; e < e1; e += 1024) atomicAdd(&h[a2c_dst[e] >> 7], 1);
        __syncthreads();
        for (int i = tid; i < NBKT; i += 1024) {
            int c = h[i];
            base[i] = c ? atomicAdd(&bcur[i], c) : 0;
        }
        __syncthreads();
        for (int e = e0 + tid; e < e1; e += 1024) {
            int d = a2c_dst[e];
            int pos = atomicAdd(&base[d >> 7], 1);
            sorted1[pos] = ((d & 127) << 10) | a2c_src[e];
        }
    }
}

// ---------------- phase 3b: scatter2 ----------------
// blocks [0,256): c2a pass2 — per-range 1000-bin counting scatter sorted_c2a -> col_c2a
//   (32 blocks per range over the contiguous range segment).
// blocks [256,256+NBKT): per-bucket a2c client CSR (rp_c + col_a2c).
__global__ __launch_bounds__(1024) void scatter2(const int* __restrict__ sorted_c2a,
                                                 const int* __restrict__ rp_ar,
                                                 int* __restrict__ cur_ar,
                                                 int* __restrict__ col_c2a, int E,
                                                 const int* __restrict__ brp,
                                                 const int* __restrict__ sorted1,
                                                 int* __restrict__ rp_c,
                                                 int* __restrict__ col_a2c) {
    __shared__ int sb[2 * NAGG];
    int tid = threadIdx.x;
    if (blockIdx.x < 256) {
        int* h = sb;           // [1000]
        int* base = sb + NAGG; // [1000]
        int r = blockIdx.x >> 5, k = blockIdx.x & 31;
        int seg0 = rp_ar[r * NAGG];
        int seg1 = rp_ar[(r + 1) * NAGG];   // rp_ar[8000] = E for r=7
        int chunk = (seg1 - seg0 + 31) / 32;
        int e0 = seg0 + k * chunk;
        int e1 = min(seg1, e0 + chunk);
        for (int i = tid; i < NAGG; i += 1024) h[i] = 0;
        __syncthreads();
        for (int e = e0 + tid; e < e1; e += 1024) atomicAdd(&h[sorted_c2a[e] >> 17], 1);
        __syncthreads();
        for (int i = tid; i < NAGG; i += 1024) {
            int c = h[i];
            base[i] = c ? atomicAdd(&cur_ar[r * NAGG + i], c) : 0;
        }
        __syncthreads();
        for (int e = e0 + tid; e < e1; e += 1024) {
            int p = sorted_c2a[e];
            int pos = atomicAdd(&base[p >> 17], 1);
            col_c2a[pos] = p & 0x1FFFF;
        }
    } else {
        int* h = sb;          // [128]
        int* cur = sb + 128;  // [128]
        int b = blockIdx.x - 256;
        if (tid < 128) h[tid] = 0;
        __syncthreads();
        int beg = brp[b], end = brp[b + 1];
        for (int e = beg + tid; e < end; e += 1024) atomicAdd(&h[sorted1[e] >> 10], 1);
        __syncthreads();
        if (tid < 128) cur[tid] = h[tid];
        __syncthreads();
        for (int off = 1; off < 128; off <<= 1) {
            int x = 0;
            if (tid < 128 && tid >= off) x = cur[tid - off];
            __syncthreads();
            if (tid < 128) cur[tid] += x;
            __syncthreads();
        }
        if (tid < 128) {
            int start = beg + cur[tid] - h[tid];
            int c = b * 128 + tid;
            if (c < NCLI) rp_c[c] = start;
            cur[tid] = start;
        }
        if (b == NBKT - 1 && tid == 0) rp_c[NCLI] = end;
        __syncthreads();
        for (int e = beg + tid; e < end; e += 1024) {
            int p = sorted1[e];
            int pos = atomicAdd(&cur[p >> 10], 1);
            col_a2c[pos] = p & 1023;
        }
    }
}

// ---------------- layer kernels ----------------

// XCD-sliced mean gather: blockIdx = quad*8 + range; bin = range*NAGG + agg.
__global__ __launch_bounds__(512) void gather_mean(const unsigned* __restrict__ tbl,
                                                   const int* __restrict__ rp_ar,
                                                   const int* __restrict__ col,
                                                   float* __restrict__ psum) {
    __shared__ float part[4][8][D];   // 16 KB
    int quad = blockIdx.x >> 3, r = blockIdx.x & 7;
    int tid = threadIdx.x;
    int a = tid >> 7;            // local agg 0..3
    int sub = (tid >> 4) & 7;    // reader 0..7
    int sl = tid & 15;           // lane in reader
    const uint4* tbl4 = (const uint4*)tbl;
    int agg = quad * 4 + a;
    int bin = r * NAGG + agg;
    int beg = rp_ar[bin], end = rp_ar[bin + 1];
    float f0 = 0, f1 = 0, f2 = 0, f3 = 0, f4 = 0, f5 = 0, f6 = 0, f7 = 0;
    int e = beg + sub;
    for (; e + 8 < end; e += 16) {   // 2 edges in flight per reader
        int s0 = col[e];
        int s1 = col[e + 8];
        uint4 v0 = tbl4[(s0 << 4) + sl];
        uint4 v1 = tbl4[(s1 << 4) + sl];
        f0 += bf_lo(v0.x); f1 += bf_hi(v0.x); f2 += bf_lo(v0.y); f3 += bf_hi(v0.y);
        f4 += bf_lo(v0.z); f5 += bf_hi(v0.z); f6 += bf_lo(v0.w); f7 += bf_hi(v0.w);
        f0 += bf_lo(v1.x); f1 += bf_hi(v1.x); f2 += bf_lo(v1.y); f3 += bf_hi(v1.y);
        f4 += bf_lo(v1.z); f5 += bf_hi(v1.z); f6 += bf_lo(v1.w); f7 += bf_hi(v1.w);
    }
    if (e < end) {
        int s0 = col[e];
        uint4 v0 = tbl4[(s0 << 4) + sl];
        f0 += bf_lo(v0.x); f1 += bf_hi(v0.x); f2 += bf_lo(v0.y); f3 += bf_hi(v0.y);
        f4 += bf_lo(v0.z); f5 += bf_hi(v0.z); f6 += bf_lo(v0.w); f7 += bf_hi(v0.w);
    }
    float* pr = &part[a][sub][sl * 8];
    pr[0] = f0; pr[1] = f1; pr[2] = f2; pr[3] = f3;
    pr[4] = f4; pr[5] = f5; pr[6] = f6; pr[7] = f7;
    __syncthreads();
    int c = tid & 127;
    float s = 0.f;
#pragma unroll
    for (int g = 0; g < 8; g++) s += part[a][g][c];
    psum[((size_t)agg * NRNG + r) * D + c] = s;
}

// combine partials -> mean; then ya = xa@Wl_a2c (bf16), xa_new = leaky(mean@Wl_c2a + xa@Wr_c2a + b)
__global__ __launch_bounds__(128) void combine_agg(const float* __restrict__ psum,
                                                   const int* __restrict__ rp_ar,
                                                   const float* xa_old,
                                                   const float* __restrict__ Wl_a2c,
                                                   const float* __restrict__ Wl_c2a,
                                                   const float* __restrict__ Wr_c2a,
                                                   const float* __restrict__ b_c2a,
                                                   unsigned short* __restrict__ ya_bf,
                                                   float* xa_out) {
    __shared__ float mr[D], xr[D];
    int i = blockIdx.x, j = threadIdx.x;
    const float* pr = psum + (size_t)i * NRNG * D + j;
    float s = 0.f;
#pragma unroll
    for (int r = 0; r < NRNG; r++) s += pr[r * D];
    int deg = 0;
#pragma unroll
    for (int r = 0; r < NRNG; r++) deg += rp_ar[r * NAGG + i + 1] - rp_ar[r * NAGG + i];
    mr[j] = s / fmaxf((float)deg, 1.f);
    xr[j] = xa_old[i * D + j];
    __syncthreads();
    float accy = 0.f, accn = b_c2a[j];
#pragma unroll 4
    for (int k = 0; k < D; k++) {
        accy += xr[k] * Wl_a2c[k * D + j];
        accn += mr[k] * Wl_c2a[k * D + j] + xr[k] * Wr_c2a[k * D + j];
    }
    ya_bf[i * D + j] = (unsigned short)bf16_rn(accy);
    xa_out[i * D + j] = leaky(accn);
}

// Persistent split-bf16 MFMA gemm, 32x32x16 (R10-proven). B fragments register-resident.
__global__ __launch_bounds__(256) void gemm_mfma(const unsigned short* __restrict__ Ahi,
                                                 const unsigned short* __restrict__ Alo,
                                                 const unsigned short* __restrict__ Wt,
                                                 const float* __restrict__ bias,
                                                 float* __restrict__ Y) {
    int tid = threadIdx.x;
    int wave = tid >> 6, lane = tid & 63;
    int cl = lane & 31, kh = lane >> 5;
    int n0 = wave * 32;
    const unsigned short* Wlo = Wt + D * D;
    const unsigned short* wbh = Wt + (size_t)(n0 + cl) * D + kh * 8;
    const unsigned short* wbl = Wlo + (size_t)(n0 + cl) * D + kh * 8;
    bf16x8 bhi[8], blo[8];
#pragma unroll
    for (int kc = 0; kc < 8; kc++) {
        bhi[kc] = *(const bf16x8*)(wbh + kc * 16);
        blo[kc] = *(const bf16x8*)(wbl + kc * 16);
    }
    float bv = bias[n0 + cl];
    for (int r = blockIdx.x; r < NROWT; r += gridDim.x) {
        int m0 = r * 32;
        const unsigned short* ar = Ahi + (size_t)(m0 + cl) * D + kh * 8;
        const unsigned short* al = Alo + (size_t)(m0 + cl) * D + kh * 8;
        bf16x8 ahi[8], alo[8];
#pragma unroll
        for (int kc = 0; kc < 8; kc++) {
            ahi[kc] = *(const bf16x8*)(ar + kc * 16);
            alo[kc] = *(const bf16x8*)(al + kc * 16);
        }
        f32x16 acc;
#pragma unroll
        for (int q = 0; q < 16; q++) acc[q] = bv;
#pragma unroll
        for (int kc = 0; kc < 8; kc++) {
            acc = __builtin_amdgcn_mfma_f32_32x32x16_bf16(ahi[kc], bhi[kc], acc, 0, 0, 0);
            acc = __builtin_amdgcn_mfma_f32_32x32x16_bf16(alo[kc], bhi[kc], acc, 0, 0, 0);
            acc = __builtin_amdgcn_mfma_f32_32x32x16_bf16(ahi[kc], blo[kc], acc, 0, 0, 0);
        }
        float* yb = Y + (size_t)m0 * D + n0 + cl;
#pragma unroll
        for (int reg = 0; reg < 16; reg++) {
            int row = (reg & 3) + 8 * (reg >> 2) + 4 * kh;
            yb[(size_t)row * D] = acc[reg];
        }
    }
}

// xc = leaky(Yb + mean_e ya_bf[col[e]]) — R7-proven scalar version.
template <int LAST>
__global__ __launch_bounds__(256) void agg_c_bf(const unsigned* __restrict__ ya,
                                                const int* __restrict__ rowptr,
                                                const int* __restrict__ col,
                                                const float* __restrict__ Y,
                                                unsigned* __restrict__ xhi,
                                                unsigned* __restrict__ xlo,
                                                const float* __restrict__ Wlin,
                                                const float* __restrict__ blin,
                                                float* __restrict__ out, int E) {
    int l = threadIdx.x & 63;
    int gid = blockIdx.x * 4 + (threadIdx.x >> 6);
    if (gid >= NCLI) return;
    int beg = rowptr[gid], end = rowptr[gid + 1];
    float a0 = 0, b0 = 0, a1 = 0, b1 = 0, a2 = 0, b2 = 0, a3 = 0, b3 = 0;
    float a4 = 0, b4 = 0, a5 = 0, b5 = 0, a6 = 0, b6 = 0, a7 = 0, b7 = 0;
    for (int ch = beg; ch < end; ch += 64) {
        int len = min(64, end - ch);
        int ec = col[min(ch + l, E - 1)];
        int j = 0;
        for (; j + 8 <= len; j += 8) {
            int r0 = __shfl(ec, j + 0), r1 = __shfl(ec, j + 1);
            int r2 = __shfl(ec, j + 2), r3 = __shfl(ec, j + 3);
            int r4 = __shfl(ec, j + 4), r5 = __shfl(ec, j + 5);
            int r6 = __shfl(ec, j + 6), r7 = __shfl(ec, j + 7);
            unsigned v0 = ya[(r0 << 6) + l];
            unsigned v1 = ya[(r1 << 6) + l];
            unsigned v2 = ya[(r2 << 6) + l];
            unsigned v3 = ya[(r3 << 6) + l];
            unsigned v4 = ya[(r4 << 6) + l];
            unsigned v5 = ya[(r5 << 6) + l];
            unsigned v6 = ya[(r6 << 6) + l];
            unsigned v7 = ya[(r7 << 6) + l];
            a0 += bf_lo(v0); b0 += bf_hi(v0);
            a1 += bf_lo(v1); b1 += bf_hi(v1);
            a2 += bf_lo(v2); b2 += bf_hi(v2);
            a3 += bf_lo(v3); b3 += bf_hi(v3);
            a4 += bf_lo(v4); b4 += bf_hi(v4);
            a5 += bf_lo(v5); b5 += bf_hi(v5);
            a6 += bf_lo(v6); b6 += bf_hi(v6);
            a7 += bf_lo(v7); b7 += bf_hi(v7);
        }
        for (; j < len; j++) {
            int r = __shfl(ec, j);
            unsigned v = ya[(r << 6) + l];
            a0 += bf_lo(v); b0 += bf_hi(v);
        }
    }
    float sx = ((a0 + a1) + (a2 + a3)) + ((a4 + a5) + (a6 + a7));
    float sy = ((b0 + b1) + (b2 + b3)) + ((b4 + b5) + (b6 + b7));
    float inv = 1.f / fmaxf((float)(end - beg), 1.f);
    float2 yv = *(const float2*)&Y[(size_t)gid * D + 2 * l];
    float r0 = leaky(yv.x + sx * inv);
    float r1 = leaky(yv.y + sy * inv);
    if (LAST) {
        float2 w = *(const float2*)&Wlin[2 * l];
        float v = r0 * w.x + r1 * w.y;
#pragma unroll
        for (int off = 32; off > 0; off >>= 1) v += __shfl_down(v, off);
        if (l == 0) out[gid] = v + blin[0];
    } else {
        unsigned h0 = bf16_rn(r0), h1 = bf16_rn(r1);
        xhi[(gid << 6) + l] = h0 | (h1 << 16);
        xlo[(gid << 6) + l] = pack_bf2(r0 - bf_val(h0), r1 - bf_val(h1));
    }
}

extern "C" void kernel_launch(void* const* d_in, const int* in_sizes, int n_in,
                              void* d_out, int out_size, void* d_ws, size_t ws_size,
                              hipStream_t stream) {
    const float* x_clients = (const float*)d_in[0];
    const float* x_agg     = (const float*)d_in[1];
    const int*   c2a_src   = (const int*)d_in[2];
    const int*   c2a_dst   = (const int*)d_in[3];
    const int*   a2c_src   = (const int*)d_in[4];
    const int*   a2c_dst   = (const int*)d_in[5];
    const float* Wl_c2a    = (const float*)d_in[6];
    const float* Wr_c2a    = (const float*)d_in[7];
    const float* b_c2a     = (const float*)d_in[8];
    const float* Wl_a2c    = (const float*)d_in[9];
    const float* Wr_a2c    = (const float*)d_in[10];
    const float* b_a2c     = (const float*)d_in[11];
    const float* W_lin     = (const float*)d_in[12];
    const float* b_lin     = (const float*)d_in[13];
    float* out = (float*)d_out;
    const int E = in_sizes[2];

    char* p = (char*)d_ws;
    auto alloc = [&](size_t bytes) {
        char* r = p;
        p += (bytes + 255) & ~(size_t)255;
        return r;
    };
    float*    Yb    = (float*)alloc(sizeof(float) * NCLI * D);         // gemm output (f32)
    unsigned* xc_hi = (unsigned*)alloc(sizeof(unsigned) * NCLI * 64);  // bf16 hi (also gather tbl)
    unsigned* xc_lo = (unsigned*)alloc(sizeof(unsigned) * NCLI * 64);  // bf16 lo
    float*    xa    = (float*)alloc(sizeof(float) * NAGG * D);
    unsigned short* ya_bf = (unsigned short*)alloc(sizeof(unsigned short) * NAGG * D);
    unsigned short* Wt = (unsigned short*)alloc(sizeof(unsigned short) * NLAYER * 2 * D * D);
    float* psum  = (float*)alloc(sizeof(float) * NAGG * NRNG * D);     // 4 MB gather partials
    int* cnt_ar = (int*)alloc(sizeof(int) * (NBIN + NBKT));  // cnt_ar + bcnt
    int* bcnt  = cnt_ar + NBIN;
    int* rp_ar = (int*)alloc(sizeof(int) * (NBIN + 1));
    int* cur_ar = (int*)alloc(sizeof(int) * NBIN);
    int* cur_r8 = (int*)alloc(sizeof(int) * NRNG);
    int* brp   = (int*)alloc(sizeof(int) * (NBKT + 1));
    int* bcur  = (int*)alloc(sizeof(int) * NBKT);
    int* rp_c  = (int*)alloc(sizeof(int) * (NCLI + 1));
    int* col_c2a = (int*)alloc(sizeof(int) * E);
    int* col_a2c = (int*)alloc(sizeof(int) * E);
    // sorted1 / sorted_c2a alias Yb (2E ints <= NCLI*D floats): dead before layer-0 gemm writes Yb
    int* sorted1    = (int*)Yb;
    int* sorted_c2a = sorted1 + E;

    hipMemsetAsync(cnt_ar, 0, sizeof(int) * (NBIN + NBKT), stream);

    prep<<<NHIST + NCVTX + NCVTW, 256, 0, stream>>>(c2a_src, c2a_dst, a2c_dst, E, cnt_ar, bcnt,
                                                    (const float4*)x_clients,
                                                    (uint2*)xc_hi, (uint2*)xc_lo,
                                                    Wr_a2c, Wt);
    scan_both<<<2, 1024, 0, stream>>>(cnt_ar, rp_ar, cur_ar, cur_r8, bcnt, brp, bcur);
    scatter1<<<320, 1024, 0, stream>>>(c2a_src, c2a_dst, a2c_src, a2c_dst, E,
                                       cur_r8, sorted_c2a, bcur, sorted1);
    scatter2<<<256 + NBKT, 1024, 0, stream>>>(sorted_c2a, rp_ar, cur_ar, col_c2a, E,
                                              brp, sorted1, rp_c, col_a2c);

    const float* xa_old = x_agg;
    for (int l = 0; l < NLAYER; l++) {
        gather_mean<<<(NAGG / 4) * NRNG, 512, 0, stream>>>(xc_hi, rp_ar, col_c2a, psum);
        combine_agg<<<NAGG, 128, 0, stream>>>(psum, rp_ar, xa_old,
                                              Wl_a2c + l * D * D, Wl_c2a + l * D * D,
                                              Wr_c2a + l * D * D, b_c2a + l * D, ya_bf, xa);
        gemm_mfma<<<625, 256, 0, stream>>>(
            (const unsigned short*)xc_hi, (const unsigned short*)xc_lo,
            Wt + l * 2 * D * D, b_a2c + l * D, Yb);
        if (l < NLAYER - 1) {
            agg_c_bf<0><<<(NCLI + 3) / 4, 256, 0, stream>>>((const unsigned*)ya_bf, rp_c, col_a2c,
                                                            Yb, xc_hi, xc_lo, nullptr, nullptr,
                                                            nullptr, E);
        } else {
            agg_c_bf<1><<<(NCLI + 3) / 4, 256, 0, stream>>>((const unsigned*)ya_bf, rp_c, col_a2c,
                                                            Yb, nullptr, nullptr, W_lin, b_lin,
                                                            out, E);
        }
        xa_old = xa;
    }
}